// Round 2
// baseline (289.857 us; speedup 1.0000x reference)
//
#include <hip/hip_runtime.h>
#include <hip/hip_bf16.h>

#define NMOD 64
#define INPD 256
#define OUTD 256
#define BATCH 2048
#define TT 64

typedef __attribute__((ext_vector_type(8))) short short8;
typedef __attribute__((ext_vector_type(4))) float floatx4;

__device__ __forceinline__ unsigned int pack2(float a, float b) {
    union { float f; unsigned int u; } ua, ub; ua.f = a; ub.f = b;
    unsigned int ra = ua.u + 0x7fffu + ((ua.u >> 16) & 1u);
    unsigned int rb = ub.u + 0x7fffu + ((ub.u >> 16) & 1u);
    return (ra >> 16) | (rb & 0xffff0000u);
}

// Repack W [e][n][k] f32 -> fragment-major bf16:
//   Wpack elem index = (((e*8 + ks)*16 + frag)*64 + lane)*8 + j
//   frag = w*4 + ni  (wave w owns cols w*64..w*64+63; ni = 16-col group)
//   source n = (frag>>3)*128 + (frag&7)*16 + (lane&15)
//   source k = ks*32 + (lane>>4)*8 + j
// GEMM B-loads then become lane-contiguous 1024B bursts.
__global__ __launch_bounds__(256) void conv_w_kernel(const float* __restrict__ W,
                                                     uint4* __restrict__ Wp) {
    int gid  = blockIdx.x * 256 + threadIdx.x;   // 0 .. 524287 (one 8-elem frag slice)
    int lane = gid & 63;
    int frag = (gid >> 6) & 15;
    int ks   = (gid >> 10) & 7;
    int e    = gid >> 13;

    int n = (frag >> 3) * 128 + (frag & 7) * 16 + (lane & 15);
    int k = ks * 32 + (lane >> 4) * 8;

    const float* p = W + ((size_t)e * OUTD + n) * INPD + k;
    float4 v0 = *reinterpret_cast<const float4*>(p);
    float4 v1 = *reinterpret_cast<const float4*>(p + 4);
    Wp[gid] = make_uint4(pack2(v0.x, v0.y), pack2(v0.z, v0.w),
                         pack2(v1.x, v1.y), pack2(v1.z, v1.w));
}

// One block per sample, 4 waves; wave w owns output cols [w*64, w*64+64).
// K split in two halves; ONE 16 KiB fragment-major LDS buffer per block:
//   slot s = (kk*4 + mi)*64 + lane, 16 B each  (kk = ks&3)
// Staging: thread tid writes slots r*256+tid (tid-contiguous ds_write_b128,
// conflict-free); gemm reads slot base + lane*16 (conflict-free).
// 16 KiB LDS + <=64 VGPR -> 8 blocks/CU resident (32 waves, full occupancy):
// cross-block TLP hides W-load latency and interleaves stage/store HBM bursts.
// MFMA operands SWAPPED (W as A-op, x as B-op) -> float4 stores + float4 bias.
template <bool PRECONV>
__global__ __launch_bounds__(256, 8) void moe_gemm_kernel(
    const float* __restrict__ x, const int* __restrict__ idx,
    const void* __restrict__ Wsrc, const float* __restrict__ bias,
    float* __restrict__ y) {

    __shared__ unsigned short lx[4 * 4 * 64 * 8];   // 16 KiB, one K-half

    const int b    = blockIdx.x;
    const int tid  = threadIdx.x;
    const int lane = tid & 63;
    const int w    = tid >> 6;
    const int e    = idx[b];
    const int l15  = lane & 15;
    const int kq   = lane >> 4;

    char* lxc = reinterpret_cast<char*>(lx);

    // Staging source: this thread's slots are s = r*256 + tid  (r = 0..3)
    //   -> kk = r, mi = w, lane = lane  =>  t = w*16 + l15, k = (h*4+r)*32 + kq*8
    const float* xrow = x + (size_t)b * (TT * INPD) + (size_t)(w * 16 + l15) * INPD + kq * 8;

    const unsigned short* wp0 = nullptr;
    const float* Wf = nullptr;
    if (PRECONV) {
        wp0 = reinterpret_cast<const unsigned short*>(Wsrc)
              + ((size_t)e << 16) + (w << 11) + (lane << 3);
    } else {
        Wf = reinterpret_cast<const float*>(Wsrc) + (size_t)e * OUTD * INPD;
    }

    floatx4 acc[4][4] = {};

#pragma unroll
    for (int h = 0; h < 2; ++h) {
        if (h) __syncthreads();   // all waves done reading the buffer for half 0

        // ---- stage K-half h: load f32, pack to bf16, fragment-major ds_write ----
#pragma unroll
        for (int r = 0; r < 4; ++r) {
            const float* p = xrow + (h * 4 + r) * 32;
            float4 v0 = *reinterpret_cast<const float4*>(p);
            float4 v1 = *reinterpret_cast<const float4*>(p + 4);
            *reinterpret_cast<uint4*>(lxc + ((r * 256 + tid) << 4)) =
                make_uint4(pack2(v0.x, v0.y), pack2(v0.z, v0.w),
                           pack2(v1.x, v1.y), pack2(v1.z, v1.w));
        }
        __syncthreads();

        // ---- compute 4 K-steps of this half ----
#pragma unroll
        for (int kk = 0; kk < 4; ++kk) {
            const int ks = h * 4 + kk;

            short8 af[4];
#pragma unroll
            for (int mi = 0; mi < 4; ++mi)
                af[mi] = *reinterpret_cast<const short8*>(
                    lxc + ((((kk * 4 + mi) * 64) + lane) << 4));

            short8 bf[4];
            if (PRECONV) {
                const unsigned short* wp = wp0 + ((size_t)ks << 13);
#pragma unroll
                for (int ni = 0; ni < 4; ++ni)
                    bf[ni] = *reinterpret_cast<const short8*>(wp + (ni << 9));
            } else {
#pragma unroll
                for (int ni = 0; ni < 4; ++ni) {
                    int n = w * 64 + ni * 16 + l15;
                    int k = ks * 32 + kq * 8;
                    const float* p = Wf + (size_t)n * INPD + k;
                    float4 v0 = *reinterpret_cast<const float4*>(p);
                    float4 v1 = *reinterpret_cast<const float4*>(p + 4);
                    union { short8 s; uint4 u; } cv;
                    cv.u = make_uint4(pack2(v0.x, v0.y), pack2(v0.z, v0.w),
                                      pack2(v1.x, v1.y), pack2(v1.z, v1.w));
                    bf[ni] = cv.s;
                }
            }

            // Swapped operands: D[m=o][n=t] = sum_k W[o][k] * x[t][k]
#pragma unroll
            for (int mi = 0; mi < 4; ++mi)
#pragma unroll
                for (int ni = 0; ni < 4; ++ni)
                    acc[mi][ni] = __builtin_amdgcn_mfma_f32_16x16x32_bf16(
                        bf[ni], af[mi], acc[mi][ni], 0, 0, 0);
        }
    }

    // Epilogue. D layout (swapped): col = lane&15 -> token within mi-group,
    // row = kq*4 + r -> output col within ni-group => lane holds 4 consecutive
    // output cols for one token: float4 store, float4 bias.
    const floatx4* bp = reinterpret_cast<const floatx4*>(bias + e * OUTD + w * 64) + kq;
    floatx4 bv[4];
#pragma unroll
    for (int ni = 0; ni < 4; ++ni)
        bv[ni] = bp[ni * 4];

    float* yb = y + (size_t)b * (TT * OUTD) + (size_t)l15 * OUTD + w * 64 + kq * 4;
#pragma unroll
    for (int mi = 0; mi < 4; ++mi) {
        float* yrow = yb + mi * (16 * OUTD);
#pragma unroll
        for (int ni = 0; ni < 4; ++ni)
            *reinterpret_cast<floatx4*>(yrow + ni * 16) = acc[mi][ni] + bv[ni];
    }
}

extern "C" void kernel_launch(void* const* d_in, const int* in_sizes, int n_in,
                              void* d_out, int out_size, void* d_ws, size_t ws_size,
                              hipStream_t stream) {
    const float* x    = (const float*)d_in[0];   // [2048, 64, 256] f32
    const int*   idx  = (const int*)d_in[1];     // [2048] i32
    const float* W    = (const float*)d_in[2];   // [64, 256, 256] f32
    const float* bias = (const float*)d_in[3];   // [64, 256] f32
    float*       y    = (float*)d_out;           // [2048, 64, 256] f32

    const size_t w_elems      = (size_t)NMOD * OUTD * INPD;          // 4,194,304
    const size_t w_bf16_bytes = w_elems * sizeof(unsigned short);    // 8 MiB

    if (ws_size >= w_bf16_bytes) {
        conv_w_kernel<<<(unsigned)(w_elems / 8 / 256), 256, 0, stream>>>(
            W, reinterpret_cast<uint4*>(d_ws));
        moe_gemm_kernel<true><<<BATCH, 256, 0, stream>>>(x, idx, d_ws, bias, y);
    } else {
        moe_gemm_kernel<false><<<BATCH, 256, 0, stream>>>(x, idx, (const void*)W, bias, y);
    }
}

// Round 3
// 104.236 us; speedup vs baseline: 2.7808x; 2.7808x over previous
//
#include <hip/hip_runtime.h>
#include <hip/hip_bf16.h>

#define NMOD 64
#define INPD 256
#define OUTD 256
#define BATCH 2048
#define TT 64

typedef __attribute__((ext_vector_type(8))) short short8;
typedef __attribute__((ext_vector_type(4))) float floatx4;

__device__ __forceinline__ unsigned int pack2(float a, float b) {
    union { float f; unsigned int u; } ua, ub; ua.f = a; ub.f = b;
    unsigned int ra = ua.u + 0x7fffu + ((ua.u >> 16) & 1u);
    unsigned int rb = ub.u + 0x7fffu + ((ub.u >> 16) & 1u);
    return (ra >> 16) | (rb & 0xffff0000u);
}

// Repack W [e][n][k] f32 -> fragment-major bf16:
//   Wpack elem index = (((e*8 + ks)*16 + frag)*64 + lane)*8 + j
//   frag = w*4 + ni  (wave w owns cols w*64..w*64+63; ni = 16-col group)
//   source n = (frag>>3)*128 + (frag&7)*16 + (lane&15)
//   source k = ks*32 + (lane>>4)*8 + j
// GEMM B-loads then become lane-contiguous 1024B bursts.
__global__ __launch_bounds__(256) void conv_w_kernel(const float* __restrict__ W,
                                                     uint4* __restrict__ Wp) {
    int gid  = blockIdx.x * 256 + threadIdx.x;   // 0 .. 524287 (one 8-elem frag slice)
    int lane = gid & 63;
    int frag = (gid >> 6) & 15;
    int ks   = (gid >> 10) & 7;
    int e    = gid >> 13;

    int n = (frag >> 3) * 128 + (frag & 7) * 16 + (lane & 15);
    int k = ks * 32 + (lane >> 4) * 8;

    const float* p = W + ((size_t)e * OUTD + n) * INPD + k;
    float4 v0 = *reinterpret_cast<const float4*>(p);
    float4 v1 = *reinterpret_cast<const float4*>(p + 4);
    Wp[gid] = make_uint4(pack2(v0.x, v0.y), pack2(v0.z, v0.w),
                         pack2(v1.x, v1.y), pack2(v1.z, v1.w));
}

// TWO blocks per sample (token-split): block = 32 tokens x 256 cols.
// 4 waves; wave w owns cols [w*64, w*64+64), tile 32x64 -> acc[2][4] = 32 regs.
// Small accumulator + 16 KiB LDS -> 5 blocks/CU resident (launch_bounds cap
// 102 regs), ~62% occupancy; finer stage/compute/store phases interleave the
// HBM bursts across blocks. ONE barrier per block.
// LDS is fragment-major (round-2-verified): slot s = (ks*2 + mi)*64 + lane,
// 16 B each. ds_write tid-contiguous, ds_read lane-contiguous: conflict-free.
// MFMA operands SWAPPED (W as A-op, x as B-op) -> float4 stores + float4 bias.
template <bool PRECONV>
__global__ __launch_bounds__(256, 5) void moe_gemm_kernel(
    const float* __restrict__ x, const int* __restrict__ idx,
    const void* __restrict__ Wsrc, const float* __restrict__ bias,
    float* __restrict__ y) {

    __shared__ unsigned short lx[8 * 2 * 64 * 8];   // 16 KiB: 32 tokens x 256 k, bf16

    const int bb   = blockIdx.x;
    const int b    = bb >> 1;
    const int t0   = (bb & 1) * 32;                 // token offset of this block
    const int tid  = threadIdx.x;
    const int lane = tid & 63;
    const int w    = tid >> 6;
    const int e    = idx[b];
    const int l15  = lane & 15;
    const int kq   = lane >> 4;

    char* lxc = reinterpret_cast<char*>(lx);

    // ---- stage 32x256 f32 -> bf16 LDS, fragment-major ----
    // thread writes slots s = r*256 + tid (r = 0..3); s -> ksmi = s>>6 = r*4+w
    //   ks = ksmi>>1, mi = ksmi&1  =>  src t = t0 + mi*16 + l15, k = ks*32 + kq*8
    const float* xb = x + (size_t)b * (TT * INPD);
#pragma unroll
    for (int r = 0; r < 4; ++r) {
        int ksmi = r * 4 + w;
        int t    = t0 + (ksmi & 1) * 16 + l15;
        int k    = (ksmi >> 1) * 32 + kq * 8;
        const float* p = xb + (size_t)t * INPD + k;
        float4 v0 = *reinterpret_cast<const float4*>(p);
        float4 v1 = *reinterpret_cast<const float4*>(p + 4);
        *reinterpret_cast<uint4*>(lxc + ((r * 256 + tid) << 4)) =
            make_uint4(pack2(v0.x, v0.y), pack2(v0.z, v0.w),
                       pack2(v1.x, v1.y), pack2(v1.z, v1.w));
    }
    __syncthreads();

    const unsigned short* wp0 = nullptr;
    const float* Wf = nullptr;
    if (PRECONV) {
        wp0 = reinterpret_cast<const unsigned short*>(Wsrc)
              + ((size_t)e << 16) + (w << 11) + (lane << 3);
    } else {
        Wf = reinterpret_cast<const float*>(Wsrc) + (size_t)e * OUTD * INPD;
    }

    floatx4 acc[2][4] = {};

#pragma unroll
    for (int ks = 0; ks < 8; ++ks) {
        // A fragments: lane holds x[t0 + mi*16 + l15][ks*32 + kq*8 .. +7]
        short8 af[2];
#pragma unroll
        for (int mi = 0; mi < 2; ++mi)
            af[mi] = *reinterpret_cast<const short8*>(
                lxc + ((((ks * 2 + mi) * 64) + lane) << 4));

        // B fragments: lane holds W[w*64 + ni*16 + l15][ks*32 + kq*8 .. +7]
        short8 bf[4];
        if (PRECONV) {
            const unsigned short* wp = wp0 + ((size_t)ks << 13);
#pragma unroll
            for (int ni = 0; ni < 4; ++ni)
                bf[ni] = *reinterpret_cast<const short8*>(wp + (ni << 9));
        } else {
#pragma unroll
            for (int ni = 0; ni < 4; ++ni) {
                int n = w * 64 + ni * 16 + l15;
                int k = ks * 32 + kq * 8;
                const float* p = Wf + (size_t)n * INPD + k;
                float4 v0 = *reinterpret_cast<const float4*>(p);
                float4 v1 = *reinterpret_cast<const float4*>(p + 4);
                union { short8 s; uint4 u; } cv;
                cv.u = make_uint4(pack2(v0.x, v0.y), pack2(v0.z, v0.w),
                                  pack2(v1.x, v1.y), pack2(v1.z, v1.w));
                bf[ni] = cv.s;
            }
        }

        // Swapped operands: D[m=o][n=t] = sum_k W[o][k] * x[t][k]
#pragma unroll
        for (int mi = 0; mi < 2; ++mi)
#pragma unroll
            for (int ni = 0; ni < 4; ++ni)
                acc[mi][ni] = __builtin_amdgcn_mfma_f32_16x16x32_bf16(
                    bf[ni], af[mi], acc[mi][ni], 0, 0, 0);
    }

    // Epilogue. D layout (swapped): col = lane&15 -> token within mi-group,
    // row = kq*4 + r -> output col within ni-group => lane holds 4 consecutive
    // output cols for one token: float4 store, float4 bias.
    const floatx4* bp = reinterpret_cast<const floatx4*>(bias + e * OUTD + w * 64) + kq;
    floatx4 bv[4];
#pragma unroll
    for (int ni = 0; ni < 4; ++ni)
        bv[ni] = bp[ni * 4];

    float* yb = y + (size_t)b * (TT * OUTD) + (size_t)(t0 + l15) * OUTD + w * 64 + kq * 4;
#pragma unroll
    for (int mi = 0; mi < 2; ++mi) {
        float* yrow = yb + mi * (16 * OUTD);
#pragma unroll
        for (int ni = 0; ni < 4; ++ni)
            *reinterpret_cast<floatx4*>(yrow + ni * 16) = acc[mi][ni] + bv[ni];
    }
}

extern "C" void kernel_launch(void* const* d_in, const int* in_sizes, int n_in,
                              void* d_out, int out_size, void* d_ws, size_t ws_size,
                              hipStream_t stream) {
    const float* x    = (const float*)d_in[0];   // [2048, 64, 256] f32
    const int*   idx  = (const int*)d_in[1];     // [2048] i32
    const float* W    = (const float*)d_in[2];   // [64, 256, 256] f32
    const float* bias = (const float*)d_in[3];   // [64, 256] f32
    float*       y    = (float*)d_out;           // [2048, 64, 256] f32

    const size_t w_elems      = (size_t)NMOD * OUTD * INPD;          // 4,194,304
    const size_t w_bf16_bytes = w_elems * sizeof(unsigned short);    // 8 MiB

    if (ws_size >= w_bf16_bytes) {
        conv_w_kernel<<<(unsigned)(w_elems / 8 / 256), 256, 0, stream>>>(
            W, reinterpret_cast<uint4*>(d_ws));
        moe_gemm_kernel<true><<<BATCH * 2, 256, 0, stream>>>(x, idx, d_ws, bias, y);
    } else {
        moe_gemm_kernel<false><<<BATCH * 2, 256, 0, stream>>>(x, idx, (const void*)W, bias, y);
    }
}

// Round 4
// 94.829 us; speedup vs baseline: 3.0566x; 1.0992x over previous
//
#include <hip/hip_runtime.h>
#include <hip/hip_bf16.h>

#define NMOD 64
#define INPD 256
#define OUTD 256
#define BATCH 2048
#define TT 64

typedef __attribute__((ext_vector_type(8))) short short8;
typedef __attribute__((ext_vector_type(4))) float floatx4;

__device__ __forceinline__ unsigned int pack2(float a, float b) {
    union { float f; unsigned int u; } ua, ub; ua.f = a; ub.f = b;
    unsigned int ra = ua.u + 0x7fffu + ((ua.u >> 16) & 1u);
    unsigned int rb = ub.u + 0x7fffu + ((ub.u >> 16) & 1u);
    return (ra >> 16) | (rb & 0xffff0000u);
}

// Repack W [e][n][k] f32 -> fragment-major bf16:
//   Wpack elem index = (((e*8 + ks)*16 + frag)*64 + lane)*8 + j
//   frag = cg*4 + ni  (col group cg owns cols cg*64..cg*64+63; ni = 16-col group)
//   source n = (frag>>3)*128 + (frag&7)*16 + (lane&15)
//   source k = ks*32 + (lane>>4)*8 + j
// GEMM B-loads then become lane-contiguous 1024B bursts.
__global__ __launch_bounds__(256) void conv_w_kernel(const float* __restrict__ W,
                                                     uint4* __restrict__ Wp) {
    int gid  = blockIdx.x * 256 + threadIdx.x;   // 0 .. 524287 (one 8-elem frag slice)
    int lane = gid & 63;
    int frag = (gid >> 6) & 15;
    int ks   = (gid >> 10) & 7;
    int e    = gid >> 13;

    int n = (frag >> 3) * 128 + (frag & 7) * 16 + (lane & 15);
    int k = ks * 32 + (lane >> 4) * 8;

    const float* p = W + ((size_t)e * OUTD + n) * INPD + k;
    float4 v0 = *reinterpret_cast<const float4*>(p);
    float4 v1 = *reinterpret_cast<const float4*>(p + 4);
    Wp[gid] = make_uint4(pack2(v0.x, v0.y), pack2(v0.z, v0.w),
                         pack2(v1.x, v1.y), pack2(v1.z, v1.w));
}

// ONE block per sample (W read once -> L2-friendly, round-0/3 lesson), but
// EIGHT waves (512 threads) so the per-thread accumulator is only 32 regs
// (round-2 lesson: 64-reg acc caps occupancy at ~36%).
// Wave w: rg = w>>2 (token half, 32 rows), cg = w&3 (col quarter, 64 cols).
// Full x[b] (64x256) staged once as bf16 in 32 KiB fragment-major LDS:
//   slot s = (ks*4 + mi)*64 + lane, 16 B  (token = mi*16 + l15, k = ks*32+kq*8)
// ds_write tid-contiguous, ds_read lane-contiguous: conflict-free.
// launch_bounds(512,6): 85-reg cap, 3 blocks/CU (24 waves, 75% occ), 96 KiB LDS.
// MFMA operands SWAPPED (W as A-op, x as B-op) -> float4 stores + float4 bias.
template <bool PRECONV>
__global__ __launch_bounds__(512, 6) void moe_gemm_kernel(
    const float* __restrict__ x, const int* __restrict__ idx,
    const void* __restrict__ Wsrc, const float* __restrict__ bias,
    float* __restrict__ y) {

    __shared__ unsigned short lx[8 * 4 * 64 * 8];   // 32 KiB: 64 tokens x 256 k, bf16

    const int b    = blockIdx.x;
    const int tid  = threadIdx.x;
    const int lane = tid & 63;
    const int w    = tid >> 6;        // 0..7
    const int rg   = w >> 2;          // token half
    const int cg   = w & 3;           // col quarter
    const int e    = idx[b];
    const int l15  = lane & 15;
    const int kq   = lane >> 4;

    char* lxc = reinterpret_cast<char*>(lx);

    // ---- stage 64x256 f32 -> bf16 LDS, fragment-major ----
    // thread writes slots s = r*512 + tid (r=0..3); ksmi = s>>6 = r*8 + w
    //   ks = ksmi>>2, mi = ksmi&3  =>  src t = mi*16 + l15, k = ks*32 + kq*8
    const float* xb = x + (size_t)b * (TT * INPD);
#pragma unroll
    for (int r = 0; r < 4; ++r) {
        int ksmi = r * 8 + w;
        int t    = (ksmi & 3) * 16 + l15;
        int k    = (ksmi >> 2) * 32 + kq * 8;
        const float* p = xb + (size_t)t * INPD + k;
        float4 v0 = *reinterpret_cast<const float4*>(p);
        float4 v1 = *reinterpret_cast<const float4*>(p + 4);
        *reinterpret_cast<uint4*>(lxc + ((r * 512 + tid) << 4)) =
            make_uint4(pack2(v0.x, v0.y), pack2(v0.z, v0.w),
                       pack2(v1.x, v1.y), pack2(v1.z, v1.w));
    }
    __syncthreads();

    const unsigned short* wp0 = nullptr;
    const float* Wf = nullptr;
    if (PRECONV) {
        // elem = (e*8+ks)*8192 + (cg*4+ni)*512 + lane*8
        wp0 = reinterpret_cast<const unsigned short*>(Wsrc)
              + ((size_t)e << 16) + (cg << 11) + (lane << 3);
    } else {
        Wf = reinterpret_cast<const float*>(Wsrc) + (size_t)e * OUTD * INPD;
    }

    floatx4 acc[2][4] = {};

#pragma unroll
    for (int ks = 0; ks < 8; ++ks) {
        // A fragments: lane holds x[(rg*2+j)*16 + l15][ks*32 + kq*8 .. +7]
        short8 af[2];
#pragma unroll
        for (int j = 0; j < 2; ++j)
            af[j] = *reinterpret_cast<const short8*>(
                lxc + ((((ks * 4 + rg * 2 + j) * 64) + lane) << 4));

        // B fragments: lane holds W[cg*64 + ni*16 + l15][ks*32 + kq*8 .. +7]
        short8 bf[4];
        if (PRECONV) {
            const unsigned short* wp = wp0 + ((size_t)ks << 13);
#pragma unroll
            for (int ni = 0; ni < 4; ++ni)
                bf[ni] = *reinterpret_cast<const short8*>(wp + (ni << 9));
        } else {
#pragma unroll
            for (int ni = 0; ni < 4; ++ni) {
                int n = cg * 64 + ni * 16 + l15;
                int k = ks * 32 + kq * 8;
                const float* p = Wf + (size_t)n * INPD + k;
                float4 v0 = *reinterpret_cast<const float4*>(p);
                float4 v1 = *reinterpret_cast<const float4*>(p + 4);
                union { short8 s; uint4 u; } cv;
                cv.u = make_uint4(pack2(v0.x, v0.y), pack2(v0.z, v0.w),
                                  pack2(v1.x, v1.y), pack2(v1.z, v1.w));
                bf[ni] = cv.s;
            }
        }

        // Swapped operands: D[m=o][n=t] = sum_k W[o][k] * x[t][k]
#pragma unroll
        for (int j = 0; j < 2; ++j)
#pragma unroll
            for (int ni = 0; ni < 4; ++ni)
                acc[j][ni] = __builtin_amdgcn_mfma_f32_16x16x32_bf16(
                    bf[ni], af[j], acc[j][ni], 0, 0, 0);
    }

    // Epilogue. D layout (swapped): col = lane&15 -> token within j-group,
    // row = kq*4 + r -> output col within ni-group => lane holds 4 consecutive
    // output cols for one token: float4 store, float4 bias.
    const floatx4* bp = reinterpret_cast<const floatx4*>(bias + e * OUTD + cg * 64) + kq;
    floatx4 bv[4];
#pragma unroll
    for (int ni = 0; ni < 4; ++ni)
        bv[ni] = bp[ni * 4];

    float* yb = y + (size_t)b * (TT * OUTD)
              + (size_t)(rg * 32 + l15) * OUTD + cg * 64 + kq * 4;
#pragma unroll
    for (int j = 0; j < 2; ++j) {
        float* yrow = yb + j * (16 * OUTD);
#pragma unroll
        for (int ni = 0; ni < 4; ++ni)
            *reinterpret_cast<floatx4*>(yrow + ni * 16) = acc[j][ni] + bv[ni];
    }
}

extern "C" void kernel_launch(void* const* d_in, const int* in_sizes, int n_in,
                              void* d_out, int out_size, void* d_ws, size_t ws_size,
                              hipStream_t stream) {
    const float* x    = (const float*)d_in[0];   // [2048, 64, 256] f32
    const int*   idx  = (const int*)d_in[1];     // [2048] i32
    const float* W    = (const float*)d_in[2];   // [64, 256, 256] f32
    const float* bias = (const float*)d_in[3];   // [64, 256] f32
    float*       y    = (float*)d_out;           // [2048, 64, 256] f32

    const size_t w_elems      = (size_t)NMOD * OUTD * INPD;          // 4,194,304
    const size_t w_bf16_bytes = w_elems * sizeof(unsigned short);    // 8 MiB

    if (ws_size >= w_bf16_bytes) {
        conv_w_kernel<<<(unsigned)(w_elems / 8 / 256), 256, 0, stream>>>(
            W, reinterpret_cast<uint4*>(d_ws));
        moe_gemm_kernel<true><<<BATCH, 512, 0, stream>>>(x, idx, d_ws, bias, y);
    } else {
        moe_gemm_kernel<false><<<BATCH, 512, 0, stream>>>(x, idx, (const void*)W, bias, y);
    }
}

// Round 5
// 88.040 us; speedup vs baseline: 3.2924x; 1.0771x over previous
//
#include <hip/hip_runtime.h>
#include <hip/hip_bf16.h>

#define NMOD 64
#define INPD 256
#define OUTD 256
#define BATCH 2048
#define TT 64
#define SPB 4                      // samples per block (pipelined)

typedef __attribute__((ext_vector_type(8))) short short8;
typedef __attribute__((ext_vector_type(4))) float floatx4;

__device__ __forceinline__ unsigned int pack2(float a, float b) {
    union { float f; unsigned int u; } ua, ub; ua.f = a; ub.f = b;
    unsigned int ra = ua.u + 0x7fffu + ((ua.u >> 16) & 1u);
    unsigned int rb = ub.u + 0x7fffu + ((ub.u >> 16) & 1u);
    return (ra >> 16) | (rb & 0xffff0000u);
}

// Repack W [e][n][k] f32 -> fragment-major bf16 (round-0 verified layout):
//   Wpack elem index = (((e*8 + ks)*16 + frag)*64 + lane)*8 + j
//   frag = w*4 + ni  (wave w owns cols w*64..w*64+63; ni = 16-col group)
//   source n = (frag>>3)*128 + (frag&7)*16 + (lane&15)
//   source k = ks*32 + (lane>>4)*8 + j
__global__ __launch_bounds__(256) void conv_w_kernel(const float* __restrict__ W,
                                                     uint4* __restrict__ Wp) {
    int gid  = blockIdx.x * 256 + threadIdx.x;
    int lane = gid & 63;
    int frag = (gid >> 6) & 15;
    int ks   = (gid >> 10) & 7;
    int e    = gid >> 13;

    int n = (frag >> 3) * 128 + (frag & 7) * 16 + (lane & 15);
    int k = ks * 32 + (lane >> 4) * 8;

    const float* p = W + ((size_t)e * OUTD + n) * INPD + k;
    float4 v0 = *reinterpret_cast<const float4*>(p);
    float4 v1 = *reinterpret_cast<const float4*>(p + 4);
    Wp[gid] = make_uint4(pack2(v0.x, v0.y), pack2(v0.z, v0.w),
                         pack2(v1.x, v1.y), pack2(v1.z, v1.w));
}

// Round-0 tile geometry (1 sample tile, 4 waves, wave w owns cols [w*64,w*64+64),
// acc[4][4], W disjoint across waves -> W read ONCE per sample) but each block
// pipelines SPB=4 samples with a 2-deep half-K LDS double buffer:
//   step t (t = 0..7): h = t&1, s = t>>1
//     - issue global loads for half t+1 into regs     (HBM stream never drains)
//     - compute half t from lx[t&1] (ds_read + MFMA)
//     - pack + ds_write half t+1 into lx[(t+1)&1]
//     - (h==1) epilogue sample s: bias + NT float4 stores, reset acc
//     - one barrier
// Buffer safety: lx[B] written at step t was last read at step t-1 (barrier
// between); read at t+1 (barrier between). One barrier per step suffices.
// NT stores keep the write-once y stream from evicting W in L2.
template <bool PRECONV>
__global__ __launch_bounds__(256, 3) void moe_gemm_kernel(
    const float* __restrict__ x, const int* __restrict__ idx,
    const void* __restrict__ Wsrc, const float* __restrict__ bias,
    float* __restrict__ y) {

    __shared__ unsigned short lx[2][4 * 4 * 64 * 8];   // 2 x 16 KiB half-K buffers

    const int bid  = blockIdx.x;
    const int s0   = bid * SPB;
    const int tid  = threadIdx.x;
    const int lane = tid & 63;
    const int w    = tid >> 6;        // 0..3, owns cols [w*64, w*64+64)
    const int l15  = lane & 15;
    const int kq   = lane >> 4;

    int e4[SPB];
#pragma unroll
    for (int i = 0; i < SPB; ++i) e4[i] = idx[s0 + i];

    char* const lb0 = reinterpret_cast<char*>(lx[0]);
    char* const lb1 = reinterpret_cast<char*>(lx[1]);

    // Staging: thread (w,lane) owns token row t = w*16 + l15; per half it loads
    // k = (h*4+r)*32 + kq*8 .. +7 (r=0..3) and writes slot (r*4+w)*64+lane.
    // Fragment-major: slot (kk*4+mi)*64+lane holds x[mi*16+l15][kk*32+kq*8..+7]
    // => staging writes tid-contiguous, gemm reads lane-contiguous: conflict-free.
    auto stage_load = [&](int s, int h, float4* sv) {
        const float* xb = x + ((size_t)(s0 + s) * TT + w * 16 + l15) * INPD + kq * 8;
#pragma unroll
        for (int r = 0; r < 4; ++r) {
            const float* p = xb + (h * 4 + r) * 32;
            sv[2 * r]     = *reinterpret_cast<const float4*>(p);
            sv[2 * r + 1] = *reinterpret_cast<const float4*>(p + 4);
        }
    };
    auto stage_write = [&](char* lc, const float4* sv) {
#pragma unroll
        for (int r = 0; r < 4; ++r) {
            float4 a = sv[2 * r], c = sv[2 * r + 1];
            *reinterpret_cast<uint4*>(lc + ((((r * 4 + w) * 64) + lane) << 4)) =
                make_uint4(pack2(a.x, a.y), pack2(a.z, a.w),
                           pack2(c.x, c.y), pack2(c.z, c.w));
        }
    };

    floatx4 acc[4][4] = {};
    float4 sv[8];

    // prologue: stage (s=0, h=0) into buffer 0
    stage_load(0, 0, sv);
    stage_write(lb0, sv);
    __syncthreads();

#pragma unroll
    for (int t = 0; t < 2 * SPB; ++t) {
        const int s = t >> 1;
        const int h = t & 1;
        const int e = e4[s];

        // 1) issue next-half global loads (overlap with compute below)
        if (t < 2 * SPB - 1)
            stage_load((t + 1) >> 1, (t + 1) & 1, sv);

        // 2) compute current half from lx[t&1]
        char* lc = (t & 1) ? lb1 : lb0;
        const unsigned short* wp0 = nullptr;
        const float* Wf = nullptr;
        if (PRECONV) {
            wp0 = reinterpret_cast<const unsigned short*>(Wsrc)
                  + ((size_t)e << 16) + (w << 11) + (lane << 3);
        } else {
            Wf = reinterpret_cast<const float*>(Wsrc) + (size_t)e * OUTD * INPD;
        }

#pragma unroll
        for (int kk = 0; kk < 4; ++kk) {
            const int ks = h * 4 + kk;

            short8 af[4];
#pragma unroll
            for (int mi = 0; mi < 4; ++mi)
                af[mi] = *reinterpret_cast<const short8*>(
                    lc + ((((kk * 4 + mi) * 64) + lane) << 4));

            short8 bf[4];
            if (PRECONV) {
                const unsigned short* wp = wp0 + ((size_t)ks << 13);
#pragma unroll
                for (int ni = 0; ni < 4; ++ni)
                    bf[ni] = *reinterpret_cast<const short8*>(wp + (ni << 9));
            } else {
#pragma unroll
                for (int ni = 0; ni < 4; ++ni) {
                    int n = w * 64 + ni * 16 + l15;
                    int k = ks * 32 + kq * 8;
                    const float* p = Wf + (size_t)n * INPD + k;
                    float4 v0 = *reinterpret_cast<const float4*>(p);
                    float4 v1 = *reinterpret_cast<const float4*>(p + 4);
                    union { short8 sh; uint4 u; } cv;
                    cv.u = make_uint4(pack2(v0.x, v0.y), pack2(v0.z, v0.w),
                                      pack2(v1.x, v1.y), pack2(v1.z, v1.w));
                    bf[ni] = cv.sh;
                }
            }

            // Swapped operands: D[m=o][n=t] = sum_k W[o][k] * x[t][k]
#pragma unroll
            for (int mi = 0; mi < 4; ++mi)
#pragma unroll
                for (int ni = 0; ni < 4; ++ni)
                    acc[mi][ni] = __builtin_amdgcn_mfma_f32_16x16x32_bf16(
                        bf[ni], af[mi], acc[mi][ni], 0, 0, 0);
        }

        // 3) write next half into the other buffer
        if (t < 2 * SPB - 1)
            stage_write((t & 1) ? lb0 : lb1, sv);

        // 4) epilogue after second half of each sample
        if (h == 1) {
            // D layout (swapped): col = l15 -> token within mi-group,
            // row = kq*4+r -> output col => float4 store per (mi,ni).
            const floatx4* bp =
                reinterpret_cast<const floatx4*>(bias + e * OUTD + w * 64) + kq;
            floatx4 bv[4];
#pragma unroll
            for (int ni = 0; ni < 4; ++ni)
                bv[ni] = bp[ni * 4];

            float* yb = y + ((size_t)(s0 + s) * TT + l15) * OUTD + w * 64 + kq * 4;
#pragma unroll
            for (int mi = 0; mi < 4; ++mi) {
                float* yrow = yb + mi * (16 * OUTD);
#pragma unroll
                for (int ni = 0; ni < 4; ++ni) {
                    floatx4 out = acc[mi][ni] + bv[ni];
                    __builtin_nontemporal_store(
                        out, reinterpret_cast<floatx4*>(yrow + ni * 16));
                    acc[mi][ni] = (floatx4)0.0f;   // reset for next sample
                }
            }
        }

        if (t < 2 * SPB - 1)
            __syncthreads();
    }
}

extern "C" void kernel_launch(void* const* d_in, const int* in_sizes, int n_in,
                              void* d_out, int out_size, void* d_ws, size_t ws_size,
                              hipStream_t stream) {
    const float* x    = (const float*)d_in[0];   // [2048, 64, 256] f32
    const int*   idx  = (const int*)d_in[1];     // [2048] i32
    const float* W    = (const float*)d_in[2];   // [64, 256, 256] f32
    const float* bias = (const float*)d_in[3];   // [64, 256] f32
    float*       y    = (float*)d_out;           // [2048, 64, 256] f32

    const size_t w_elems      = (size_t)NMOD * OUTD * INPD;          // 4,194,304
    const size_t w_bf16_bytes = w_elems * sizeof(unsigned short);    // 8 MiB

    if (ws_size >= w_bf16_bytes) {
        conv_w_kernel<<<(unsigned)(w_elems / 8 / 256), 256, 0, stream>>>(
            W, reinterpret_cast<uint4*>(d_ws));
        moe_gemm_kernel<true><<<BATCH / SPB, 256, 0, stream>>>(x, idx, d_ws, bias, y);
    } else {
        moe_gemm_kernel<false><<<BATCH / SPB, 256, 0, stream>>>(x, idx, (const void*)W, bias, y);
    }
}

// Round 6
// 87.524 us; speedup vs baseline: 3.3117x; 1.0059x over previous
//
#include <hip/hip_runtime.h>
#include <hip/hip_bf16.h>

#define NMOD 64
#define INPD 256
#define OUTD 256
#define BATCH 2048
#define TT 64
#define SPB 2                      // samples per block (pipelined)

typedef __attribute__((ext_vector_type(8))) short short8;
typedef __attribute__((ext_vector_type(4))) float floatx4;

// RNE f32 pair -> packed bf16x2 via v_cvt_pk_bf16_f32 (same rounding as the
// old bit-trick pack2, ~1 VALU op instead of ~8).
__device__ __forceinline__ unsigned int pack2(float a, float b) {
    union { __hip_bfloat162 h; unsigned int u; } cv;
    cv.h = __float22bfloat162_rn(make_float2(a, b));
    return cv.u;
}

// Repack W [e][n][k] f32 -> fragment-major bf16 (round-0 verified layout):
//   Wpack elem index = (((e*8 + ks)*16 + frag)*64 + lane)*8 + j
//   frag = w*4 + ni  (wave w owns cols w*64..w*64+63; ni = 16-col group)
//   source n = (frag>>3)*128 + (frag&7)*16 + (lane&15)
//   source k = ks*32 + (lane>>4)*8 + j
__global__ __launch_bounds__(256) void conv_w_kernel(const float* __restrict__ W,
                                                     uint4* __restrict__ Wp) {
    int gid  = blockIdx.x * 256 + threadIdx.x;
    int lane = gid & 63;
    int frag = (gid >> 6) & 15;
    int ks   = (gid >> 10) & 7;
    int e    = gid >> 13;

    int n = (frag >> 3) * 128 + (frag & 7) * 16 + (lane & 15);
    int k = ks * 32 + (lane >> 4) * 8;

    const float* p = W + ((size_t)e * OUTD + n) * INPD + k;
    float4 v0 = *reinterpret_cast<const float4*>(p);
    float4 v1 = *reinterpret_cast<const float4*>(p + 4);
    Wp[gid] = make_uint4(pack2(v0.x, v0.y), pack2(v0.z, v0.w),
                         pack2(v1.x, v1.y), pack2(v1.z, v1.w));
}

// Round-0 tile geometry (1 sample per tile, 4 waves, wave w owns cols
// [w*64,w*64+64) => W read ONCE per sample), pipelined over SPB=2 samples
// with a 2-deep half-K LDS double buffer. Per step t (h = t&1, s = t>>1):
//   load chunk0(t+1) -> compute kk0,1(t) -> write chunk0 + load chunk1(t+1)
//   -> compute kk2,3(t) -> write chunk1 -> (h==1: epilogue s) -> barrier
// Chunked staging keeps only 16 f32 VGPRs in flight; af loaded one short8 at
// a time. Target: unified VGPR+AGPR <= 128 so 4 waves/SIMD => with grid 1024
// (4 blocks/CU) the HBM stream never drains on any CU.
// Buffer safety: buf[(t+1)&1] was last read at step t-1; barrier at end of
// t-1 separates all its readers from step-t writers (round-5 verified).
template <bool PRECONV>
__global__ __launch_bounds__(256, 4) void moe_gemm_kernel(
    const float* __restrict__ x, const int* __restrict__ idx,
    const void* __restrict__ Wsrc, const float* __restrict__ bias,
    float* __restrict__ y) {

    __shared__ unsigned short lx[2][4 * 4 * 64 * 8];   // 2 x 16 KiB half-K buffers

    const int bid  = blockIdx.x;
    const int s0   = bid * SPB;
    const int tid  = threadIdx.x;
    const int lane = tid & 63;
    const int w    = tid >> 6;        // 0..3, owns cols [w*64, w*64+64)
    const int l15  = lane & 15;
    const int kq   = lane >> 4;

    int eArr[SPB];
#pragma unroll
    for (int i = 0; i < SPB; ++i) eArr[i] = idx[s0 + i];

    char* const lb0 = reinterpret_cast<char*>(lx[0]);
    char* const lb1 = reinterpret_cast<char*>(lx[1]);

    // Thread (w,lane) stages token row w*16+l15; chunk c covers r = 2c, 2c+1,
    // i.e. k = (h*4+r)*32 + kq*8 .. +7, written to slot (r*4+w)*64+lane.
    // Fragment-major: slot (kk*4+mi)*64+lane = x[mi*16+l15][kk*32+kq*8..+7].
    // ds_write tid-contiguous, ds_read lane-contiguous: conflict-free.
    const float* xb0 = x + ((size_t)s0 * TT + w * 16 + l15) * INPD + kq * 8;

    auto load_chunk = [&](int s, int h, int c, float4* sv) {
#pragma unroll
        for (int r2 = 0; r2 < 2; ++r2) {
            int r = c * 2 + r2;
            const float* p = xb0 + (size_t)s * (TT * INPD) + (h * 4 + r) * 32;
            sv[2 * r2]     = *reinterpret_cast<const float4*>(p);
            sv[2 * r2 + 1] = *reinterpret_cast<const float4*>(p + 4);
        }
    };
    auto write_chunk = [&](char* lc, int c, const float4* sv) {
#pragma unroll
        for (int r2 = 0; r2 < 2; ++r2) {
            int r = c * 2 + r2;
            float4 a = sv[2 * r2], b2 = sv[2 * r2 + 1];
            *reinterpret_cast<uint4*>(lc + ((((r * 4 + w) * 64) + lane) << 4)) =
                make_uint4(pack2(a.x, a.y), pack2(a.z, a.w),
                           pack2(b2.x, b2.y), pack2(b2.z, b2.w));
        }
    };

    floatx4 acc[4][4] = {};
    float4 sv[4];

    // prologue: stage (s=0, h=0) fully into buffer 0
    load_chunk(0, 0, 0, sv);
    write_chunk(lb0, 0, sv);
    load_chunk(0, 0, 1, sv);
    write_chunk(lb0, 1, sv);
    __syncthreads();

#pragma unroll
    for (int t = 0; t < 2 * SPB; ++t) {
        const int s = t >> 1;
        const int h = t & 1;
        const int e = eArr[s];
        char* const lc  = (t & 1) ? lb1 : lb0;   // compile-time after unroll
        char* const ln  = (t & 1) ? lb0 : lb1;
        const bool pre  = (t < 2 * SPB - 1);
        const int  sn   = (t + 1) >> 1;
        const int  hn   = (t + 1) & 1;

        const unsigned short* wp0 = nullptr;
        const float* Wf = nullptr;
        if (PRECONV) {
            wp0 = reinterpret_cast<const unsigned short*>(Wsrc)
                  + ((size_t)e << 16) + (w << 11) + (lane << 3);
        } else {
            Wf = reinterpret_cast<const float*>(Wsrc) + (size_t)e * OUTD * INPD;
        }

        // one kk step: B frags (global, L2-resident Wpack) + 4x (ds_read A, 4 MFMA)
        auto compute_kk = [&](int kk) {
            const int ks = h * 4 + kk;
            short8 bf[4];
            if (PRECONV) {
                const unsigned short* wp = wp0 + ((size_t)ks << 13);
#pragma unroll
                for (int ni = 0; ni < 4; ++ni)
                    bf[ni] = *reinterpret_cast<const short8*>(wp + (ni << 9));
            } else {
#pragma unroll
                for (int ni = 0; ni < 4; ++ni) {
                    int n = w * 64 + ni * 16 + l15;
                    int k = ks * 32 + kq * 8;
                    const float* p = Wf + (size_t)n * INPD + k;
                    float4 v0 = *reinterpret_cast<const float4*>(p);
                    float4 v1 = *reinterpret_cast<const float4*>(p + 4);
                    union { short8 sh; uint4 u; } cv;
                    cv.u = make_uint4(pack2(v0.x, v0.y), pack2(v0.z, v0.w),
                                      pack2(v1.x, v1.y), pack2(v1.z, v1.w));
                    bf[ni] = cv.sh;
                }
            }
#pragma unroll
            for (int mi = 0; mi < 4; ++mi) {
                short8 af = *reinterpret_cast<const short8*>(
                    lc + ((((kk * 4 + mi) * 64) + lane) << 4));
#pragma unroll
                for (int ni = 0; ni < 4; ++ni)
                    acc[mi][ni] = __builtin_amdgcn_mfma_f32_16x16x32_bf16(
                        bf[ni], af, acc[mi][ni], 0, 0, 0);
            }
        };

        if (pre) load_chunk(sn, hn, 0, sv);
        compute_kk(0);
        compute_kk(1);
        if (pre) {
            write_chunk(ln, 0, sv);
            load_chunk(sn, hn, 1, sv);
        }
        compute_kk(2);
        compute_kk(3);
        if (pre) write_chunk(ln, 1, sv);

        if (h == 1) {
            // D layout (swapped operands): col = l15 -> token within mi-group,
            // row = kq*4+r -> output col => float4 store per (mi,ni).
            const floatx4* bp =
                reinterpret_cast<const floatx4*>(bias + e * OUTD + w * 64) + kq;
            floatx4 bv[4];
#pragma unroll
            for (int ni = 0; ni < 4; ++ni)
                bv[ni] = bp[ni * 4];

            float* yb = y + ((size_t)(s0 + s) * TT + l15) * OUTD + w * 64 + kq * 4;
#pragma unroll
            for (int mi = 0; mi < 4; ++mi) {
                float* yrow = yb + mi * (16 * OUTD);
#pragma unroll
                for (int ni = 0; ni < 4; ++ni) {
                    *reinterpret_cast<floatx4*>(yrow + ni * 16) = acc[mi][ni] + bv[ni];
                    if (s + 1 < SPB) acc[mi][ni] = (floatx4)0.0f;
                }
            }
        }

        if (pre) __syncthreads();
    }
}

extern "C" void kernel_launch(void* const* d_in, const int* in_sizes, int n_in,
                              void* d_out, int out_size, void* d_ws, size_t ws_size,
                              hipStream_t stream) {
    const float* x    = (const float*)d_in[0];   // [2048, 64, 256] f32
    const int*   idx  = (const int*)d_in[1];     // [2048] i32
    const float* W    = (const float*)d_in[2];   // [64, 256, 256] f32
    const float* bias = (const float*)d_in[3];   // [64, 256] f32
    float*       y    = (float*)d_out;           // [2048, 64, 256] f32

    const size_t w_elems      = (size_t)NMOD * OUTD * INPD;          // 4,194,304
    const size_t w_bf16_bytes = w_elems * sizeof(unsigned short);    // 8 MiB

    if (ws_size >= w_bf16_bytes) {
        conv_w_kernel<<<(unsigned)(w_elems / 8 / 256), 256, 0, stream>>>(
            W, reinterpret_cast<uint4*>(d_ws));
        moe_gemm_kernel<true><<<BATCH / SPB, 256, 0, stream>>>(x, idx, d_ws, bias, y);
    } else {
        moe_gemm_kernel<false><<<BATCH / SPB, 256, 0, stream>>>(x, idx, (const void*)W, bias, y);
    }
}